// Round 2
// baseline (1014.118 us; speedup 1.0000x reference)
//
#include <hip/hip_runtime.h>

#define NROWS 4096
#define NCLASS 50257
#define BLK 256
#define U 8            // float4s per thread per main-loop iteration (32 floats)
#define DEFER_THR 8.0f // T13: skip rescale unless chunk max beats m by > THR

// Stage 1: one block per row, chunked online-softmax with deferred rescale.
//
// Structure per 32-element chunk:
//   (1) 8 independent coalesced float4 loads issued together (deep pipeline)
//   (2) off-chain fmax tree for the chunk max
//   (3) rescale ONLY if cm > m + 8 (per-lane; values bounded by e^8, safe in
//       f32; cross-lane merge handles heterogeneous per-lane m). In steady
//       state no lane triggers -> exec-mask-empty branch skip -> the
//       loop-carried chain is a single fma per chunk.
//   (4) 32 independent exps summed into an off-chain partial
__global__ __launch_bounds__(BLK) void ce_row_kernel(
    const float* __restrict__ pred,
    const int* __restrict__ target,
    float* __restrict__ row_loss) {
    const int row = blockIdx.x;
    const float* __restrict__ p = pred + (size_t)row * NCLASS;
    const int tid = threadIdx.x;

    float m = -3.4e38f;
    float l = 0.0f;

    // Peel scalar head until 16B-aligned (row stride 50257*4 B is 4B-aligned).
    const int head = (int)(((16u - (unsigned)((size_t)p & 15u)) & 15u) >> 2);
    if (tid < head) {
        m = p[tid];
        l = 1.0f;
    }

    const float4* __restrict__ pv = (const float4*)(p + head);
    const int nvec = (NCLASS - head) >> 2;   // ~12564 float4s per row

    const int CHUNK = U * BLK;               // 2048 float4s per block-chunk
    const int nchunk = nvec / CHUNK;         // full chunks (~6)

    for (int c = 0; c < nchunk; ++c) {
        const int base = c * CHUNK + tid;

        // (1) batch the loads
        float4 v[U];
        #pragma unroll
        for (int k = 0; k < U; ++k) v[k] = pv[base + k * BLK];

        // (2) chunk max, off the carried chain
        float cm = -3.4e38f;
        #pragma unroll
        for (int k = 0; k < U; ++k) {
            cm = fmaxf(cm,
                       fmaxf(fmaxf(v[k].x, v[k].y), fmaxf(v[k].z, v[k].w)));
        }

        // (3) deferred rescale — rarely taken after the first chunk
        if (cm > m + DEFER_THR) {
            l *= __expf(m - cm);   // first chunk: exp(-inf)=0, l stays 0
            m = cm;
        }

        // (4) 32 independent exps (bounded by e^DEFER_THR), off-chain sum
        float s = 0.0f;
        #pragma unroll
        for (int k = 0; k < U; ++k) {
            s += __expf(v[k].x - m) + __expf(v[k].y - m)
               + __expf(v[k].z - m) + __expf(v[k].w - m);
        }
        l += s;
    }

    // remainder float4s (same deferred scheme, scalar-strided)
    for (int i = nchunk * CHUNK + tid; i < nvec; i += BLK) {
        float4 v = pv[i];
        float vm = fmaxf(fmaxf(v.x, v.y), fmaxf(v.z, v.w));
        if (vm > m + DEFER_THR) {
            l *= __expf(m - vm);
            m = vm;
        }
        l += __expf(v.x - m) + __expf(v.y - m)
           + __expf(v.z - m) + __expf(v.w - m);
    }
    // scalar tail (row length not a multiple of 4)
    for (int j = head + (nvec << 2) + tid; j < NCLASS; j += BLK) {
        float x = p[j];
        if (x > m + DEFER_THR) {
            l *= __expf(m - x);
            m = x;
        }
        l += __expf(x - m);
    }

    // wave-level reduce of (m, l) — exact online merge
    #pragma unroll
    for (int off = 32; off > 0; off >>= 1) {
        float om = __shfl_down(m, off, 64);
        float ol = __shfl_down(l, off, 64);
        float nm = fmaxf(m, om);
        l = l * __expf(m - nm) + ol * __expf(om - nm);
        m = nm;
    }

    // cross-wave reduce via LDS (4 waves)
    __shared__ float sm[BLK / 64];
    __shared__ float sl[BLK / 64];
    const int wave = tid >> 6;
    const int lane = tid & 63;
    if (lane == 0) { sm[wave] = m; sl[wave] = l; }
    __syncthreads();

    if (tid == 0) {
        m = sm[0]; l = sl[0];
        #pragma unroll
        for (int w = 1; w < BLK / 64; ++w) {
            float om = sm[w], ol = sl[w];
            float nm = fmaxf(m, om);
            l = l * __expf(m - nm) + ol * __expf(om - nm);
            m = nm;
        }
        const int t = target[row];
        row_loss[row] = -(p[t] - m - __logf(l));
    }
}

// Stage 2: single block sums the 4096 per-row losses, writes the scalar.
// Overwrites the poisoned d_out directly — no zero-init kernel needed.
__global__ __launch_bounds__(BLK) void ce_reduce_kernel(
    const float* __restrict__ row_loss,
    float* __restrict__ out) {
    const int tid = threadIdx.x;
    float s = 0.0f;
    for (int i = tid; i < NROWS; i += BLK) s += row_loss[i];

    #pragma unroll
    for (int off = 32; off > 0; off >>= 1) s += __shfl_down(s, off, 64);

    __shared__ float sw[BLK / 64];
    if ((tid & 63) == 0) sw[tid >> 6] = s;
    __syncthreads();

    if (tid == 0) {
        float t = 0.0f;
        #pragma unroll
        for (int w = 0; w < BLK / 64; ++w) t += sw[w];
        out[0] = t * (1.0f / (float)NROWS);
    }
}

extern "C" void kernel_launch(void* const* d_in, const int* in_sizes, int n_in,
                              void* d_out, int out_size, void* d_ws, size_t ws_size,
                              hipStream_t stream) {
    const float* pred = (const float*)d_in[0];
    const int* target = (const int*)d_in[1];
    float* out = (float*)d_out;
    float* row_loss = (float*)d_ws;   // 4096 floats = 16 KB scratch

    ce_row_kernel<<<NROWS, BLK, 0, stream>>>(pred, target, row_loss);
    ce_reduce_kernel<<<1, BLK, 0, stream>>>(row_loss, out);
}